// Round 4
// baseline (251.594 us; speedup 1.0000x reference)
//
#include <hip/hip_runtime.h>
#include <hip/hip_bf16.h>

#define NSEQ 2048
#define HID 128
#define HEADS 8
#define HD 16
#define SCALE 0.25f
#define TQ 16
#define TK 64
#define SPLIT 8
#define KT_PER (NSEQ / TK / SPLIT)   // 4 tiles per block
#define QROW 160            // padded q row stride (floats): 8 chunks of 20
#define PM_W 36             // P row stride in 32-bit words (64 keys = 32 words + pad)
#define PH_W (16 * PM_W + 4)  // 580: P head stride in words

typedef unsigned short ushort_t;
typedef __attribute__((ext_vector_type(8))) short short8;
typedef __attribute__((ext_vector_type(4))) float floatx4;

__device__ __forceinline__ void unpack2(unsigned u, float& a, float& b) {
    union { unsigned x; float f; } lo, hi;
    lo.x = u << 16; hi.x = u & 0xffff0000u;
    a = lo.f; b = hi.f;
}
__device__ __forceinline__ void unpack8(uint4 u, float* f) {
    unpack2(u.x, f[0], f[1]); unpack2(u.y, f[2], f[3]);
    unpack2(u.z, f[4], f[5]); unpack2(u.w, f[6], f[7]);
}
__device__ __forceinline__ unsigned pack_bf16x2(float a, float b) {
    __hip_bfloat16 ba = __float2bfloat16(a);
    __hip_bfloat16 bb = __float2bfloat16(b);
    return (unsigned)*(ushort_t*)&ba | ((unsigned)*(ushort_t*)&bb << 16);
}

// ---------------- kernel A: coalesced LDS-tile transpose of 4 weight matrices ----------------
// grid 64 blocks x 256 threads: mat = blk>>4, 16 tiles of 32x32 per 128x128 matrix
__global__ __launch_bounds__(256) void transpose_kernel(
    const float* __restrict__ Wq, const float* __restrict__ Wk,
    const float* __restrict__ Wv, const float* __restrict__ Wo,
    float* __restrict__ wt)
{
    __shared__ float ts[32][33];
    const int mat = blockIdx.x >> 4, tile = blockIdx.x & 15;
    const int r0 = (tile >> 2) * 32, c0 = (tile & 3) * 32;
    const float* W = (mat == 0) ? Wq : (mat == 1) ? Wk : (mat == 2) ? Wv : Wo;
    const int lr = threadIdx.x >> 5;      // 0..7
    const int lc = threadIdx.x & 31;
#pragma unroll
    for (int i = 0; i < 4; ++i)
        ts[lr + i * 8][lc] = W[(r0 + lr + i * 8) * HID + c0 + lc];
    __syncthreads();
    float* dst = wt + mat * 16384;
#pragma unroll
    for (int i = 0; i < 4; ++i)
        dst[(c0 + lr + i * 8) * HID + r0 + lc] = ts[lc][lr + i * 8];
}

// ---------------- kernel B: QKV projection, one matrix per block-range ----------------
// grid 1536 blocks x 128 threads; mat = blk>>9: 0->Q fp32, 1->K bf16 rows,
// 2->V bf16 TRANSPOSED (Vt[j][n], j = h*16+d). 4 rows per block.
__global__ __launch_bounds__(128) void qkv_kernel(
    const float* __restrict__ x, const float* __restrict__ WqT,
    const float* __restrict__ WkT, const float* __restrict__ WvT,
    const float* __restrict__ bq, const float* __restrict__ bk,
    const float* __restrict__ bv, float* __restrict__ Qm,
    __hip_bfloat16* __restrict__ Kb, __hip_bfloat16* __restrict__ Vt)
{
    __shared__ float xs[4 * HID];
    const int j = threadIdx.x;
    const int mat = blockIdx.x >> 9;
    const int rb = blockIdx.x & 511;
    const int r0 = rb * 4;
    const float* WT = (mat == 0) ? WqT : (mat == 1) ? WkT : WvT;
    const float* bb = (mat == 0) ? bq : (mat == 1) ? bk : bv;
    ((float4*)xs)[j] = ((const float4*)(x + (size_t)r0 * HID))[j];
    __syncthreads();
    float acc[4];
#pragma unroll
    for (int r = 0; r < 4; ++r) acc[r] = 0.f;
#pragma unroll 8
    for (int i = 0; i < HID; ++i) {
        float w = WT[i * HID + j];
#pragma unroll
        for (int r = 0; r < 4; ++r) acc[r] = fmaf(xs[r * HID + i], w, acc[r]);
    }
    float bv_ = bb[j];
#pragma unroll
    for (int r = 0; r < 4; ++r) acc[r] += bv_;
    if (mat == 0) {
#pragma unroll
        for (int r = 0; r < 4; ++r) Qm[(size_t)(r0 + r) * HID + j] = acc[r];
    } else if (mat == 1) {
#pragma unroll
        for (int r = 0; r < 4; ++r) Kb[(size_t)(r0 + r) * HID + j] = __float2bfloat16(acc[r]);
    } else {
        // transposed store: Vt[j][r0..r0+3], 8B contiguous per thread
        unsigned u0 = pack_bf16x2(acc[0], acc[1]);
        unsigned u1 = pack_bf16x2(acc[2], acc[3]);
        *(uint2*)((ushort_t*)Vt + (size_t)j * NSEQ + r0) = make_uint2(u0, u1);
    }
}

// ---------------- kernel C: fused attention, split-K, MFMA PV ----------------
// grid 128*SPLIT blocks x 256 threads; block = TQ=16 query rows, 256 keys
__global__ __launch_bounds__(256, 4) void attn_kernel(
    const float* __restrict__ Qm, const __hip_bfloat16* __restrict__ Kb,
    const __hip_bfloat16* __restrict__ Vt, const float* __restrict__ bias,
    const unsigned char* __restrict__ mask, float* __restrict__ Op,
    float* __restrict__ Lp)
{
    __shared__ float qs[TQ * QROW];      // 10.2 KB padded fp32 q
    __shared__ float Pbuf[8 * PH_W];     // 18.1 KB: P bf16 tile; reused as obuf in epilogue
    __shared__ float wl[4 * TQ * HEADS]; // 2 KB per-wave l partials

    const int t = threadIdx.x;
    const int lane = t & 63;
    const int wid = t >> 6;
    const int qb = blockIdx.x & 127;
    const int sp = blockIdx.x >> 7;
    const int n0 = qb * TQ;

    // score roles
    const int sc_mp = t >> 3;          // 0..31 -> key pair
    const int sc_h  = t & 7;
    // PV roles
    const int kk = wid & 1;            // K-half of the 64-key tile
    const int hbase = (wid >> 1) * 4;  // 4 heads per wave-pair
    const int frag_m = lane & 15;
    const int frag_q = lane >> 4;

    {   // load q tile (2048 floats) into padded layout
        for (int idx = t; idx < 512; idx += 256) {
            int r = idx >> 5, c = idx & 31;
            int h = c >> 2, dg = c & 3;
            float4 v = ((const float4*)(Qm + (size_t)n0 * HID))[idx];
            *(float4*)&qs[r * QROW + h * 20 + dg * 4] = v;
        }
    }
    floatx4 acc[4];
#pragma unroll
    for (int hh = 0; hh < 4; ++hh) acc[hh] = (floatx4){0.f, 0.f, 0.f, 0.f};
    float lsum[TQ];
#pragma unroll
    for (int r = 0; r < TQ; ++r) lsum[r] = 0.0f;
    __syncthreads();

    for (int kt = 0; kt < KT_PER; ++kt) {
        const int m0 = (sp * KT_PER + kt) * TK;
        // ---- phase 1: fp32 scores + exp -> P (bf16) ----
        {
            const int m1 = m0 + sc_mp * 2;
            // hoisted: batch-issue ALL 32 bias loads for this tile first
            float bb0[TQ], bb1[TQ];
            const float* bp = bias + ((size_t)n0 * NSEQ + m1) * HEADS + sc_h;
#pragma unroll
            for (int r = 0; r < TQ; ++r) {
                bb0[r] = bp[(size_t)r * (NSEQ * HEADS)];
                bb1[r] = bp[(size_t)r * (NSEQ * HEADS) + HEADS];
            }
            const ushort_t* kp = (const ushort_t*)Kb + (size_t)m1 * HID + sc_h * HD;
            uint4 ka = *(const uint4*)kp;
            uint4 kb2 = *(const uint4*)(kp + 8);
            uint4 kc = *(const uint4*)(kp + HID);
            uint4 kd = *(const uint4*)(kp + HID + 8);
            float k0[16], k1[16];
            unpack8(ka, k0); unpack8(kb2, k0 + 8);
            unpack8(kc, k1); unpack8(kd, k1 + 8);
            const bool msk0 = mask[m1] != 0;
            const bool msk1 = mask[m1 + 1] != 0;
            unsigned* Pw = (unsigned*)Pbuf;
#pragma unroll
            for (int r = 0; r < TQ; ++r) {
                const float* qr = &qs[r * QROW + sc_h * 20];
                float qf[16];
                *(float4*)&qf[0]  = *(const float4*)(qr);
                *(float4*)&qf[4]  = *(const float4*)(qr + 4);
                *(float4*)&qf[8]  = *(const float4*)(qr + 8);
                *(float4*)&qf[12] = *(const float4*)(qr + 12);
                float d0 = 0.f, d1 = 0.f;
#pragma unroll
                for (int i = 0; i < 16; ++i) {
                    d0 = fmaf(qf[i], k0[i], d0);
                    d1 = fmaf(qf[i], k1[i], d1);
                }
                float s0 = fmaf(d0, SCALE, bb0[r]);
                float s1 = fmaf(d1, SCALE, bb1[r]);
                if (msk0) s0 = -INFINITY;
                if (msk1) s1 = -INFINITY;
                float e0 = __expf(s0);
                float e1 = __expf(s1);
                lsum[r] += e0 + e1;
                Pw[sc_h * PH_W + r * PM_W + sc_mp] = pack_bf16x2(e0, e1);
            }
        }
        __syncthreads();
        // ---- phase 2: PV via MFMA ----
        {
            const unsigned* Pw = (const unsigned*)Pbuf;
#pragma unroll
            for (int hh = 0; hh < 4; ++hh) {
                const int h = hbase + hh;
                const ushort_t* vrow = (const ushort_t*)Vt +
                    ((size_t)(h * HD + frag_m)) * NSEQ + m0 + kk * 32 + frag_q * 8;
                short8 bfrag = *(const short8*)vrow;
                short8 afrag = *(const short8*)&Pw[h * PH_W + frag_m * PM_W + kk * 16 + frag_q * 4];
                acc[hh] = __builtin_amdgcn_mfma_f32_16x16x32_bf16(afrag, bfrag, acc[hh], 0, 0, 0);
            }
        }
        __syncthreads();
    }

    // ---- epilogue ----
    // reduce lsum over key-pairs within wave (lane bits 3..5)
#pragma unroll
    for (int r = 0; r < TQ; ++r) {
        lsum[r] += __shfl_xor(lsum[r], 8);
        lsum[r] += __shfl_xor(lsum[r], 16);
        lsum[r] += __shfl_xor(lsum[r], 32);
    }
    if (lane < 8) {
#pragma unroll
        for (int r = 0; r < TQ; ++r)
            wl[wid * (TQ * HEADS) + r * 8 + lane] = lsum[r];
    }
    // stash O partials (two kk halves) in Pbuf-as-float
    {
        float* obuf = Pbuf;
#pragma unroll
        for (int hh = 0; hh < 4; ++hh) {
#pragma unroll
            for (int reg = 0; reg < 4; ++reg) {
                int m = frag_q * 4 + reg;
                obuf[kk * 2048 + (hbase + hh) * 256 + m * 16 + frag_m] = acc[hh][reg];
            }
        }
    }
    __syncthreads();
    if (t < 128) {
        const float* obuf = Pbuf;
#pragma unroll
        for (int r = 0; r < TQ; ++r) {
            int h = t >> 4, d = t & 15;
            float v = obuf[h * 256 + r * 16 + d] + obuf[2048 + h * 256 + r * 16 + d];
            Op[((size_t)sp * NSEQ + n0 + r) * HID + t] = v;
        }
        const int r2 = t >> 3, h2 = t & 7;
        float l = wl[r2 * 8 + h2] + wl[128 + r2 * 8 + h2] +
                  wl[256 + r2 * 8 + h2] + wl[384 + r2 * 8 + h2];
        Lp[((size_t)sp * NSEQ + n0 + r2) * HEADS + h2] = l;
    }
}

// ---------------- kernel D: combine splits + output projection ----------------
// grid 1024 blocks x 128 threads, 2 rows per block
__global__ __launch_bounds__(128) void proj_kernel(
    const float* __restrict__ Op, const float* __restrict__ Lp,
    const float* __restrict__ WoT, const float* __restrict__ bo,
    float* __restrict__ out)
{
    __shared__ float xs[2 * HID];
    const int j = threadIdx.x;
    const int r0 = blockIdx.x * 2;
    const int hh = j >> 4;
#pragma unroll
    for (int r = 0; r < 2; ++r) {
        const size_t n = r0 + r;
        float s = 0.f, l = 0.f;
#pragma unroll
        for (int sp = 0; sp < SPLIT; ++sp) {
            s += Op[((size_t)sp * NSEQ + n) * HID + j];
            l += Lp[((size_t)sp * NSEQ + n) * HEADS + hh];
        }
        xs[r * HID + j] = s / l;
    }
    __syncthreads();
    float acc[2];
    acc[0] = 0.f; acc[1] = 0.f;
#pragma unroll 8
    for (int i = 0; i < HID; ++i) {
        float w = WoT[i * HID + j];
        acc[0] = fmaf(xs[i], w, acc[0]);
        acc[1] = fmaf(xs[HID + i], w, acc[1]);
    }
    float b = bo[j];
    out[(size_t)r0 * HID + j] = acc[0] + b;
    out[(size_t)(r0 + 1) * HID + j] = acc[1] + b;
}

extern "C" void kernel_launch(void* const* d_in, const int* in_sizes, int n_in,
                              void* d_out, int out_size, void* d_ws, size_t ws_size,
                              hipStream_t stream) {
    const float* x    = (const float*)d_in[0];
    const float* bias = (const float*)d_in[1];
    const unsigned char* mask = (const unsigned char*)d_in[2];
    const float* Wq = (const float*)d_in[3];
    const float* bq = (const float*)d_in[4];
    const float* Wk = (const float*)d_in[5];
    const float* bk = (const float*)d_in[6];
    const float* Wv = (const float*)d_in[7];
    const float* bv = (const float*)d_in[8];
    const float* Wo = (const float*)d_in[9];
    const float* bo = (const float*)d_in[10];
    float* out = (float*)d_out;

    float* w = (float*)d_ws;
    // ws layout (float offsets):
    float* WqT = w;                                     // 16384
    float* WkT = w + 16384;
    float* WvT = w + 32768;
    float* WoT = w + 49152;
    float* Qm  = w + 65536;                             // 262144 fp32
    __hip_bfloat16* Kb = (__hip_bfloat16*)(w + 327680); // 262144 bf16 rows [n][j]
    __hip_bfloat16* Vt = (__hip_bfloat16*)(w + 458752); // 262144 bf16 TRANSPOSED [j][n]
    float* Op  = w + 589824;                            // SPLIT*262144 fp32 (8 MB)
    float* Lp  = w + 589824 + (size_t)SPLIT * NSEQ * HID; // SPLIT*2048*8 fp32
    // total ~11.3 MB

    transpose_kernel<<<64, 256, 0, stream>>>(Wq, Wk, Wv, Wo, w);
    qkv_kernel<<<1536, 128, 0, stream>>>(x, WqT, WkT, WvT, bq, bk, bv, Qm, Kb, Vt);
    attn_kernel<<<128 * SPLIT, 256, 0, stream>>>(Qm, Kb, Vt, bias, mask, Op, Lp);
    proj_kernel<<<1024, 128, 0, stream>>>(Op, Lp, WoT, bo, out);
}